// Round 2
// baseline (462.832 us; speedup 1.0000x reference)
//
#include <hip/hip_runtime.h>

#define NROWS 65536      // 32*2048 flattened rows
#define KC    1024       // codebook entries
#define DIM   128
#define NCHUNK 4
#define KCHUNK (KC / NCHUNK)   // 256

// numpy pairwise_sum for n=128: 8 stride-8 accumulators, 16 sequential adds
// each, then ((r0+r1)+(r2+r3))+((r4+r5)+(r6+r7)). All adds/muls in rn,
// no fma contraction (__f*_rn intrinsics).
__device__ __forceinline__ float np_sumsq_128(const float* v) {
    float r[8];
    #pragma unroll
    for (int j = 0; j < 8; ++j) r[j] = __fmul_rn(v[j], v[j]);
    #pragma unroll
    for (int i = 1; i < 16; ++i) {
        #pragma unroll
        for (int j = 0; j < 8; ++j)
            r[j] = __fadd_rn(r[j], __fmul_rn(v[i * 8 + j], v[i * 8 + j]));
    }
    return __fadd_rn(__fadd_rn(__fadd_rn(r[0], r[1]), __fadd_rn(r[2], r[3])),
                     __fadd_rn(__fadd_rn(r[4], r[5]), __fadd_rn(r[6], r[7])));
}

// ---------------------------------------------------------------------------
// ws layout:
//   [0,8)              double loss_sum
//   [64, 64+4096)      float norms[1024]
//   [8192, +1MB)       float pvals[NCHUNK][NROWS]
//   [8192+1MB, +1MB)   int   pkeys[NCHUNK][NROWS]
// ---------------------------------------------------------------------------

__global__ __launch_bounds__(256) void vq_norms(const float* __restrict__ emb,
                                                float* __restrict__ norms) {
    int k = blockIdx.x * 256 + threadIdx.x;   // one thread per codebook row
    if (k >= KC) return;
    float v[DIM];
    const float4* e = reinterpret_cast<const float4*>(emb + (size_t)k * DIM);
    #pragma unroll
    for (int i = 0; i < 32; ++i) {
        float4 t = e[i];
        v[i * 4 + 0] = t.x; v[i * 4 + 1] = t.y;
        v[i * 4 + 2] = t.z; v[i * 4 + 3] = t.w;
    }
    norms[k] = np_sumsq_128(v);
}

__global__ __launch_bounds__(256) void vq_partial(
        const float* __restrict__ x, const float* __restrict__ emb,
        const float* __restrict__ norms,
        float* __restrict__ pvals, int* __restrict__ pkeys) {
    const int r = blockIdx.x * 256 + threadIdx.x;   // row this lane owns
    const int chunk = blockIdx.y;                   // K-chunk this block scans

    const float4* xr = reinterpret_cast<const float4*>(x + (size_t)r * DIM);
    float xv[DIM];
    #pragma unroll
    for (int i = 0; i < 32; ++i) {
        float4 t = xr[i];
        xv[i * 4 + 0] = t.x; xv[i * 4 + 1] = t.y;
        xv[i * 4 + 2] = t.z; xv[i * 4 + 3] = t.w;
    }
    const float xnorm = np_sumsq_128(xv);   // numpy-pairwise ||x||^2

    float best = 3.402823466e38f;
    int bestk = 0;
    const int k0 = chunk * KCHUNK;

    #pragma unroll 2
    for (int k = k0; k < k0 + KCHUNK; ++k) {
        // k is wave-uniform -> these become scalar (s_load) reads
        const float4* e = reinterpret_cast<const float4*>(emb + (size_t)k * DIM);
        float d0 = 0.f, d1 = 0.f, d2 = 0.f, d3 = 0.f;  // 4 indep FMA chains
        #pragma unroll
        for (int i = 0; i < 32; ++i) {
            float4 ev = e[i];
            d0 = fmaf(xv[i * 4 + 0], ev.x, d0);
            d1 = fmaf(xv[i * 4 + 1], ev.y, d1);
            d2 = fmaf(xv[i * 4 + 2], ev.z, d2);
            d3 = fmaf(xv[i * 4 + 3], ev.w, d3);
        }
        float dot = __fadd_rn(__fadd_rn(d0, d1), __fadd_rn(d2, d3));
        // replicate numpy elementwise rounding: (||x||^2 + ||e||^2) - 2*mm
        float t1 = __fadd_rn(xnorm, norms[k]);
        float m2 = __fmul_rn(2.0f, dot);        // exact
        float s  = __fsub_rn(t1, m2);
        if (s < best) { best = s; bestk = k; }  // strict < : lowest k on ties
    }
    pvals[(size_t)chunk * NROWS + r] = best;
    pkeys[(size_t)chunk * NROWS + r] = bestk;
}

__global__ __launch_bounds__(256) void vq_finalize(
        const float* __restrict__ x, const float* __restrict__ emb,
        const float* __restrict__ pvals, const int* __restrict__ pkeys,
        float* __restrict__ quant, float* __restrict__ idx_out,
        double* __restrict__ loss_sum) {
    const int r = blockIdx.x * 256 + threadIdx.x;

    float best = 3.402823466e38f;
    int bestk = 0;
    #pragma unroll
    for (int c = 0; c < NCHUNK; ++c) {   // ascending chunk = ascending k range
        float v = pvals[(size_t)c * NROWS + r];
        int kk = pkeys[(size_t)c * NROWS + r];
        if (v < best) { best = v; bestk = kk; }
    }
    idx_out[r] = (float)bestk;   // indices stored as float (whole d_out is f32)

    const float4* e  = reinterpret_cast<const float4*>(emb + (size_t)bestk * DIM);
    const float4* xr = reinterpret_cast<const float4*>(x + (size_t)r * DIM);
    float* qo = quant + (size_t)r * DIM;   // only 4B-aligned (out+1) -> scalar stores

    float acc = 0.f;
    #pragma unroll
    for (int i = 0; i < 32; ++i) {
        float4 q = e[i];
        float4 xv = xr[i];
        qo[i * 4 + 0] = q.x; qo[i * 4 + 1] = q.y;
        qo[i * 4 + 2] = q.z; qo[i * 4 + 3] = q.w;
        float dx = q.x - xv.x, dy = q.y - xv.y;
        float dz = q.z - xv.z, dw = q.w - xv.w;
        acc = fmaf(dx, dx, acc); acc = fmaf(dy, dy, acc);
        acc = fmaf(dz, dz, acc); acc = fmaf(dw, dw, acc);
    }
    #pragma unroll
    for (int off = 32; off > 0; off >>= 1) acc += __shfl_down(acc, off, 64);
    if ((threadIdx.x & 63) == 0) atomicAdd(loss_sum, (double)acc);
}

__global__ void vq_loss(const double* __restrict__ loss_sum, float* __restrict__ out) {
    // loss = q_latent + 0.25*e_latent, both numerically mean((q-x)^2)
    out[0] = (float)(*loss_sum * (1.25 / 8388608.0));
}

extern "C" void kernel_launch(void* const* d_in, const int* in_sizes, int n_in,
                              void* d_out, int out_size, void* d_ws, size_t ws_size,
                              hipStream_t stream) {
    const float* x   = (const float*)d_in[0];   // [32,2048,128] f32
    const float* emb = (const float*)d_in[1];   // [1024,128] f32

    float* out      = (float*)d_out;
    float* loss_out = out;                           // [1]
    float* quant    = out + 1;                       // [8388608]
    float* idx_out  = out + 1 + (size_t)NROWS * DIM; // [65536] as float

    char* ws = (char*)d_ws;
    double* loss_sum = (double*)ws;
    float* norms = (float*)(ws + 64);
    float* pvals = (float*)(ws + 8192);
    int*   pkeys = (int*)(ws + 8192 + (size_t)NROWS * NCHUNK * sizeof(float));

    hipMemsetAsync(loss_sum, 0, sizeof(double), stream);
    vq_norms<<<(KC + 255) / 256, 256, 0, stream>>>(emb, norms);
    vq_partial<<<dim3(NROWS / 256, NCHUNK), 256, 0, stream>>>(x, emb, norms, pvals, pkeys);
    vq_finalize<<<NROWS / 256, 256, 0, stream>>>(x, emb, pvals, pkeys, quant, idx_out, loss_sum);
    vq_loss<<<1, 1, 0, stream>>>(loss_sum, loss_out);
}